// Round 14
// baseline (273.652 us; speedup 1.0000x reference)
//
#include <hip/hip_runtime.h>
#include <hip/hip_bf16.h>
#include <hip/hip_fp16.h>
#include <math.h>

// ---------------------------------------------------------------------------
// GATv2 policy net: 2x GATv2 layer (H=2, C=32, share_weights) + edge MLP.
// CSR build = slack-bucket counting sort (128 nodes/bucket, CAP=4096 slack):
//   phaseA appends E real edges into per-bucket slack runs; easum fused.
//   phaseB computes its own bucket prefix inline (no bscan dispatch), makes
//   row_ptr, synthesizes selfloop records, places records -> recs (E+N).
// Layer 0: rank-2 decomposition (x is 2-dim): wgt0 (edge-parallel) -> wrec;
//   hagg_gemm fuses hagg0 + gemm1: h0 lives only in LDS (16KB/block),
//   phase 1 wave-per-node 6-scalar butterfly + rank-2 epilogue -> LDS,
//   phase 2 split-bf16 MFMA from LDS -> z16 (fp16).
// Layer 1: agg1 fused attention+aggregation, 2-stage software pipeline
//   (batch k+1 recs loads and gathers overlap batch k math); z1 FP16.
// Cross-lane reduces use DPP (R12: ds_swizzle hops slower).
// Unnormalized softmax (clamp 60): exp cannot overflow; same math.
// ---------------------------------------------------------------------------

typedef __attribute__((ext_vector_type(8))) short short8;
typedef __attribute__((ext_vector_type(4))) float f32x4;

#define BSH 7               // 128 nodes per bucket
#define CAP 4096            // slack per bucket (mean 2048, sigma ~45)
#define CH 4096             // edges per block in phaseA

template <int IMM>
__device__ __forceinline__ float swz(float x) {
    return __int_as_float(__builtin_amdgcn_ds_swizzle(__float_as_int(x), IMM));
}

template <int CTRL>
__device__ __forceinline__ float dpp_add(float p) {
    int t = __builtin_amdgcn_update_dpp(0, __float_as_int(p), CTRL, 0xF, 0xF, true);
    return p + __int_as_float(t);
}

// sum over the 32 lanes of this head; result in all lanes (DPP + 1 swizzle).
__device__ __forceinline__ float head_reduce(float p) {
    p = dpp_add<0xB1>(p);     // xor 1
    p = dpp_add<0x4E>(p);     // xor 2
    p = dpp_add<0x141>(p);    // xor 7 (half mirror)
    p = dpp_add<0x140>(p);    // xor 15 (row mirror)
    p += swz<0x401F>(p);      // xor 16
    return p;
}

// truncating fp32 -> (hi, lo) bf16 split
__device__ __forceinline__ short2 bsplit(float x) {
    unsigned u = __float_as_uint(x);
    short hi = (short)(u >> 16);
    float hif = __uint_as_float(u & 0xFFFF0000u);
    short lo = (short)(__float_as_uint(x - hif) >> 16);
    return make_short2(hi, lo);
}

// ---- setup: blocks 0,1 = bfrag; block 2 = init cursors + easum --------------
__global__ __launch_bounds__(512) void setup_kernel(const float* __restrict__ W1,
                                                    const float* __restrict__ Wm1,
                                                    short* __restrict__ BfW1,
                                                    short* __restrict__ BfWm,
                                                    int* __restrict__ bucket_cursor,
                                                    float* __restrict__ easum, int nbuck) {
    if (blockIdx.x == 2) {
        for (int i = threadIdx.x; i < nbuck; i += 512) bucket_cursor[i] = i * CAP;
        if (threadIdx.x < 2) easum[threadIdx.x] = 0.f;
        return;
    }
    int snt = threadIdx.x >> 6;
    int lane = threadIdx.x & 63;
    int s = snt >> 2, nt = snt & 3;
    int col = nt * 16 + (lane & 15);
    short* Bf = blockIdx.x == 0 ? BfW1 : BfWm;
#pragma unroll
    for (int j = 0; j < 8; ++j) {
        int k = s * 32 + (lane >> 4) * 8 + j;
        float v;
        if (blockIdx.x == 0) {
            v = W1[k * 64 + col];
        } else {
            v = (col < 32) ? Wm1[k * 32 + col] : Wm1[(64 + k) * 32 + (col - 32)];
        }
        short2 t = bsplit(v);
        Bf[(snt * 2 + 0) * 512 + lane * 8 + j] = t.x;
        Bf[(snt * 2 + 1) * 512 + lane * 8 + j] = t.y;
    }
}

// ---- phaseA: append E edges into slack bucket runs; easum fused -------------
__global__ __launch_bounds__(256) void phaseA_kernel(const int* __restrict__ ei,
                                                     const float2* __restrict__ ea,
                                                     int* __restrict__ bucket_cursor,
                                                     float* __restrict__ easum,
                                                     float4* __restrict__ staged,
                                                     int E, int nbuck) {
    extern __shared__ int sm[];          // lcnt[nbuck] then lbase[nbuck]
    int* lcnt = sm;
    int* lbase = sm + nbuck;
    __shared__ float r0[4], r1[4];
    int tid = threadIdx.x;
    for (int i = tid; i < nbuck; i += 256) lcnt[i] = 0;
    __syncthreads();
    int base = blockIdx.x * CH;
    int end = min(base + CH, E);
    for (int i = base + tid; i < end; i += 256) {
        int d = ei[E + i];
        atomicAdd(&lcnt[d >> BSH], 1);
    }
    __syncthreads();
    for (int i = tid; i < nbuck; i += 256) {
        int c = lcnt[i];
        lbase[i] = c ? atomicAdd(&bucket_cursor[i], c) : 0;
        lcnt[i] = 0;
    }
    __syncthreads();
    float s0 = 0.f, s1 = 0.f;
    for (int i = base + tid; i < end; i += 256) {
        int s = ei[i], d = ei[E + i];
        float2 v = ea[i];
        s0 += v.x; s1 += v.y;
        int b = d >> BSH;
        int pos = lbase[b] + atomicAdd(&lcnt[b], 1);
        staged[pos] = make_float4(__int_as_float(s), v.x, v.y, __int_as_float(d));
    }
#pragma unroll
    for (int o = 32; o >= 1; o >>= 1) {
        s0 += __shfl_xor(s0, o);
        s1 += __shfl_xor(s1, o);
    }
    int wave = tid >> 6;
    if ((tid & 63) == 0) { r0[wave] = s0; r1[wave] = s1; }
    __syncthreads();
    if (tid == 0) {
        atomicAdd(&easum[0], r0[0] + r0[1] + r0[2] + r0[3]);
        atomicAdd(&easum[1], r1[0] + r1[1] + r1[2] + r1[3]);
    }
}

// ---- phaseB: inline bucket prefix; per-node count+scan -> row_ptr;
//      synth selfloop at first CSR slot; place records -----------------------
__global__ __launch_bounds__(256) void phaseB_kernel(const float4* __restrict__ staged,
                                                     const int* __restrict__ bucket_cursor,
                                                     const float* __restrict__ easum,
                                                     int* __restrict__ row_ptr,
                                                     float4* __restrict__ recs,
                                                     int N, int E, int nbuck) {
    __shared__ int cnt128[128];
    __shared__ int offs[128];
    __shared__ int psum[256];
    int b = blockIdx.x;
    int n0 = b << BSH;
    int tid = threadIdx.x;
    // inline exclusive bucket prefix: sum_{j<b}(cursor[j]-j*CAP) + 128*b
    int local = 0;
    for (int j = tid; j < b; j += 256) local += bucket_cursor[j] - j * CAP;
    psum[tid] = local;
    if (tid < 128) cnt128[tid] = 0;
    __syncthreads();
    for (int st = 128; st > 0; st >>= 1) {
        if (tid < st) psum[tid] += psum[tid + st];
        __syncthreads();
    }
    int bbase = psum[0] + 128 * b;           // exclusive, incl selfloops
    int sbeg = b * CAP;
    int send = bucket_cursor[b];             // slack run end
    for (int i = sbeg + tid; i < send; i += 256) {
        int d = __float_as_int(staged[i].w);
        atomicAdd(&cnt128[d - n0], 1);
    }
    __syncthreads();
    int node = n0 + tid;
    int tot = 0;
    if (tid < 128) {
        tot = cnt128[tid] + ((node < N) ? 1 : 0);   // +1 selfloop
        offs[tid] = tot;
    }
    __syncthreads();
    for (int st = 1; st < 128; st <<= 1) {
        int v = 0;
        if (tid < 128) {
            v = offs[tid];
            if (tid >= st) v += offs[tid - st];
        }
        __syncthreads();
        if (tid < 128) offs[tid] = v;
        __syncthreads();
    }
    float inv = 1.f / (float)E;
    float m0 = easum[0] * inv, m1 = easum[1] * inv;
    if (tid < 128 && node < N) {
        int excl = bbase + offs[tid] - tot;
        row_ptr[node] = excl;
        recs[excl] = make_float4(__int_as_float(node), m0, m1, __int_as_float(node));
        offs[tid] = excl + 1;
    }
    if (b == nbuck - 1 && tid == 0) {
        int nodes = min(128, N - n0);
        row_ptr[N] = bbase + (send - sbeg) + nodes;
    }
    __syncthreads();
    for (int i = sbeg + tid; i < send; i += 256) {
        float4 r = staged[i];
        int d = __float_as_int(r.w);
        int pos = atomicAdd(&offs[d - n0], 1);
        recs[pos] = r;
    }
}

// ---- wgt0: edge-parallel layer-0 attention weights --------------------------
__global__ __launch_bounds__(256) void wgt0_kernel(const float2* __restrict__ x,
                                                   const float* __restrict__ W0,
                                                   const float* __restrict__ b0,
                                                   const float4* __restrict__ recs,
                                                   const float* __restrict__ We,
                                                   const float* __restrict__ att,
                                                   float4* __restrict__ wrec, int EP) {
    int lane = threadIdx.x & 63;
    int m = lane & 15, quad = lane >> 4;
    int c0 = quad * 8, c1 = 32 + c0;
    float w0a[8], w1a[8], ata[8], w0b[8], w1b[8], atb[8];
    float Wxa[8], Wya[8], bca[8], Wxb[8], Wyb[8], bcb[8];
#pragma unroll
    for (int j = 0; j < 8; ++j) {
        w0a[j] = We[c0 + j];  w1a[j] = We[64 + c0 + j];  ata[j] = att[c0 + j];
        w0b[j] = We[c1 + j];  w1b[j] = We[64 + c1 + j];  atb[j] = att[c1 + j];
        Wxa[j] = W0[c0 + j];  Wya[j] = W0[64 + c0 + j];  bca[j] = b0[c0 + j];
        Wxb[j] = W0[c1 + j];  Wyb[j] = W0[64 + c1 + j];  bcb[j] = b0[c1 + j];
    }
    int ntiles = (EP + 15) >> 4;
    int wid = (blockIdx.x * blockDim.x + threadIdx.x) >> 6;
    int nw = (gridDim.x * blockDim.x) >> 6;
    for (int t = wid; t < ntiles; t += nw) {
        int e = t * 16 + m;
        int ec = e < EP ? e : EP - 1;
        float4 r = recs[ec];
        int s = __float_as_int(r.x);
        int d = __float_as_int(r.w);
        float2 xs = x[s];
        float2 xd = x[d];
        float P0 = 0.f, P1 = 0.f;
#pragma unroll
        for (int j = 0; j < 8; ++j) {
            float zs = fmaf(xs.x, Wxa[j], fmaf(xs.y, Wya[j], bca[j]));
            float zd = fmaf(xd.x, Wxa[j], fmaf(xd.y, Wya[j], bca[j]));
            float t0 = zd + zs + fmaf(r.y, w0a[j], r.z * w1a[j]);
            t0 = fmaxf(t0, 0.2f * t0);
            P0 = fmaf(t0, ata[j], P0);
            float zs1 = fmaf(xs.x, Wxb[j], fmaf(xs.y, Wyb[j], bcb[j]));
            float zd1 = fmaf(xd.x, Wxb[j], fmaf(xd.y, Wyb[j], bcb[j]));
            float t1 = zd1 + zs1 + fmaf(r.y, w0b[j], r.z * w1b[j]);
            t1 = fmaxf(t1, 0.2f * t1);
            P1 = fmaf(t1, atb[j], P1);
        }
        P0 += swz<0x401F>(P0);             // quad pair (xor 16)
        P1 += swz<0x401F>(P1);
        P0 += __shfl_xor(P0, 32);          // cross-half (xor 32)
        P1 += __shfl_xor(P1, 32);
        float w0 = __expf(fminf(P0, 60.f));
        float w1 = __expf(fminf(P1, 60.f));
        if (lane < 16 && e < EP) wrec[e] = make_float4(w0, w1, xs.x, xs.y);
    }
}

// ---- hagg_gemm: fused layer-0 aggregation (rank-2) + gemm1 ------------------
// block = 64 nodes, 256 threads. Phase 1: wave w aggregates nodes
// n0+w*16..+15 serially (lanes=edges, 6-scalar butterfly, rank-2 epilogue)
// -> LDS h[64][64]. Phase 2: split-bf16 MFMA from LDS -> z16 (fp16).
__global__ __launch_bounds__(256) void hagg_gemm_kernel(
    const float4* __restrict__ wrec, const int* __restrict__ row_ptr,
    const float* __restrict__ W0, const float* __restrict__ b0,
    const float* __restrict__ bias, const short* __restrict__ Bf,
    const float* __restrict__ b1, __half* __restrict__ z16, int N) {
    __shared__ float hl[64 * 64];
    int wave = threadIdx.x >> 6;
    int lane = threadIdx.x & 63;
    int n0 = blockIdx.x * 64;
    float W0a = W0[lane], W0b = W0[64 + lane], b0c = b0[lane], bj0 = bias[lane];
    for (int t = 0; t < 16; ++t) {
        int n = n0 + wave * 16 + t;
        int row = wave * 16 + t;
        if (n >= N) { hl[row * 64 + lane] = 0.f; continue; }
        int beg = row_ptr[n], end = row_ptr[n + 1];
        float a0 = 0.f, a1 = 0.f, a2 = 0.f, c0 = 0.f, c1 = 0.f, c2 = 0.f;
        for (int i = beg + lane; i < end; i += 64) {
            float4 r = wrec[i];
            a0 += r.x; a1 = fmaf(r.x, r.z, a1); a2 = fmaf(r.x, r.w, a2);
            c0 += r.y; c1 = fmaf(r.y, r.z, c1); c2 = fmaf(r.y, r.w, c2);
        }
#pragma unroll
        for (int o = 32; o >= 1; o >>= 1) {
            a0 += __shfl_xor(a0, o); a1 += __shfl_xor(a1, o); a2 += __shfl_xor(a2, o);
            c0 += __shfl_xor(c0, o); c1 += __shfl_xor(c1, o); c2 += __shfl_xor(c2, o);
        }
        int head = lane >> 5;
        float l  = head ? c0 : a0;
        float Sx = head ? c1 : a1;
        float Sy = head ? c2 : a2;
        float num = fmaf(W0a, Sx, fmaf(W0b, Sy, b0c * l));
        float v = num / (l + 1e-16f) + bj0;
        v = (v > 0.f) ? v : expm1f(v);       // ELU
        hl[row * 64 + lane] = v;
    }
    __syncthreads();
    // phase 2: MFMA from LDS
    int m = lane & 15, quad = lane >> 4;
    int rowb = wave * 16 + m;
    f32x4 acc[4] = {{0.f, 0.f, 0.f, 0.f}, {0.f, 0.f, 0.f, 0.f},
                    {0.f, 0.f, 0.f, 0.f}, {0.f, 0.f, 0.f, 0.f}};
#pragma unroll
    for (int s = 0; s < 2; ++s) {
        const float* ap = hl + rowb * 64 + s * 32 + quad * 8;
        float4 a0 = *(const float4*)ap;
        float4 a1 = *(const float4*)(ap + 4);
        short8 ahi, alo;
        short2 t;
        t = bsplit(a0.x); ahi[0] = t.x; alo[0] = t.y;
        t = bsplit(a0.y); ahi[1] = t.x; alo[1] = t.y;
        t = bsplit(a0.z); ahi[2] = t.x; alo[2] = t.y;
        t = bsplit(a0.w); ahi[3] = t.x; alo[3] = t.y;
        t = bsplit(a1.x); ahi[4] = t.x; alo[4] = t.y;
        t = bsplit(a1.y); ahi[5] = t.x; alo[5] = t.y;
        t = bsplit(a1.z); ahi[6] = t.x; alo[6] = t.y;
        t = bsplit(a1.w); ahi[7] = t.x; alo[7] = t.y;
#pragma unroll
        for (int nt = 0; nt < 4; ++nt) {
            const short* bp = Bf + ((s * 4 + nt) * 2) * 512 + lane * 8;
            short8 bhi = *(const short8*)bp;
            short8 blo = *(const short8*)(bp + 512);
            acc[nt] = __builtin_amdgcn_mfma_f32_16x16x32_bf16(ahi, bhi, acc[nt], 0, 0, 0);
            acc[nt] = __builtin_amdgcn_mfma_f32_16x16x32_bf16(ahi, blo, acc[nt], 0, 0, 0);
            acc[nt] = __builtin_amdgcn_mfma_f32_16x16x32_bf16(alo, bhi, acc[nt], 0, 0, 0);
        }
    }
#pragma unroll
    for (int nt = 0; nt < 4; ++nt) {
        int col = nt * 16 + m;
        float bj = b1[col];
#pragma unroll
        for (int r = 0; r < 4; ++r) {
            int orow = n0 + wave * 16 + quad * 4 + r;
            if (orow < N) z16[(size_t)orow * 64 + col] = __float2half(acc[nt][r] + bj);
        }
    }
}

// ---- agg1: fused attention+aggregation, layer 1; z FP16; 2-stage pipeline ---
__global__ __launch_bounds__(256) void agg1_kernel(
    const __half* __restrict__ z, const int* __restrict__ row_ptr,
    const float4* __restrict__ recs,
    const float* __restrict__ We, const float* __restrict__ att,
    const float* __restrict__ bias, float* __restrict__ hout, int N) {
    int gtid = blockIdx.x * blockDim.x + threadIdx.x;
    int n = gtid >> 6;
    if (n >= N) return;
    n = __builtin_amdgcn_readfirstlane(n);
    int lane = threadIdx.x & 63;

    float We0 = We[lane], We1 = We[64 + lane];
    float attj = att[lane];
    float zn = __half2float(z[(size_t)n * 64 + lane]);

    int beg = row_ptr[n], end = row_ptr[n + 1];
    float ll[4] = {0.f, 0.f, 0.f, 0.f};
    float aa[4] = {0.f, 0.f, 0.f, 0.f};
    // prologue: batch 0
    float4 rc[8];
    float zv[8];
#pragma unroll
    for (int k = 0; k < 8; ++k) {
        int idx = beg + k; if (idx > end - 1) idx = end - 1;
        rc[k] = recs[idx];
    }
#pragma unroll
    for (int k = 0; k < 8; ++k) {
        int s = __builtin_amdgcn_readfirstlane(__float_as_int(rc[k].x));
        zv[k] = __half2float(z[(size_t)s * 64 + lane]);
    }
    for (int i = beg; i < end; i += 8) {
        // issue next batch recs loads (overlap with current math)
        float4 rn[8];
        int inext = i + 8;
#pragma unroll
        for (int k = 0; k < 8; ++k) {
            int idx = inext + k; if (idx > end - 1) idx = end - 1;
            rn[k] = recs[idx];
        }
        // math on current batch
#pragma unroll
        for (int k = 0; k < 8; ++k) {
            float sj = zn + zv[k] + fmaf(rc[k].y, We0, rc[k].z * We1);
            sj = fmaxf(sj, 0.2f * sj);
            float alpha = head_reduce(sj * attj);
            float w = __expf(fminf(alpha, 60.f));
            w = (i + k < end) ? w : 0.f;         // mask clamped tail
            ll[k & 3] += w;
            aa[k & 3] = fmaf(w, zv[k], aa[k & 3]);
        }
        // issue next batch gathers (overlap with next iteration's math)
#pragma unroll
        for (int k = 0; k < 8; ++k) {
            int s = __builtin_amdgcn_readfirstlane(__float_as_int(rn[k].x));
            zv[k] = __half2float(z[(size_t)s * 64 + lane]);
            rc[k] = rn[k];
        }
    }
    float l = (ll[0] + ll[1]) + (ll[2] + ll[3]);
    float a = (aa[0] + aa[1]) + (aa[2] + aa[3]);
    float v = a / (l + 1e-16f) + bias[lane];
    v = (v > 0.f) ? v : expm1f(v);
    hout[(size_t)n * 64 + lane] = v;
}

// ---- out[N x 64] = h[N x 64] @ B[64 x 64], split-bf16 MFMA, fp16 out --------
// gvec fold: block 0 threads 0-31 also compute the goal vector.
__global__ __launch_bounds__(256) void mfma_gemm64(const float* __restrict__ h,
                                                   const short* __restrict__ Bf,
                                                   __half* __restrict__ out, int N,
                                                   const float* __restrict__ Wm1,
                                                   const float* __restrict__ bm1,
                                                   const int* __restrict__ dest,
                                                   float* __restrict__ gv) {
    int wave = threadIdx.x >> 6;
    int lane = threadIdx.x & 63;
    int n0 = blockIdx.x * 64 + wave * 16;
    if (n0 < N) {
        int m = lane & 15, quad = lane >> 4;
        int arow = n0 + m;
        if (arow > N - 1) arow = N - 1;
        f32x4 acc[4] = {{0.f, 0.f, 0.f, 0.f}, {0.f, 0.f, 0.f, 0.f},
                        {0.f, 0.f, 0.f, 0.f}, {0.f, 0.f, 0.f, 0.f}};
#pragma unroll
        for (int s = 0; s < 2; ++s) {
            const float* ap = h + (size_t)arow * 64 + s * 32 + quad * 8;
            float4 a0 = *(const float4*)ap;
            float4 a1 = *(const float4*)(ap + 4);
            short8 ahi, alo;
            short2 t;
            t = bsplit(a0.x); ahi[0] = t.x; alo[0] = t.y;
            t = bsplit(a0.y); ahi[1] = t.x; alo[1] = t.y;
            t = bsplit(a0.z); ahi[2] = t.x; alo[2] = t.y;
            t = bsplit(a0.w); ahi[3] = t.x; alo[3] = t.y;
            t = bsplit(a1.x); ahi[4] = t.x; alo[4] = t.y;
            t = bsplit(a1.y); ahi[5] = t.x; alo[5] = t.y;
            t = bsplit(a1.z); ahi[6] = t.x; alo[6] = t.y;
            t = bsplit(a1.w); ahi[7] = t.x; alo[7] = t.y;
#pragma unroll
            for (int nt = 0; nt < 4; ++nt) {
                const short* bp = Bf + ((s * 4 + nt) * 2) * 512 + lane * 8;
                short8 bhi = *(const short8*)bp;
                short8 blo = *(const short8*)(bp + 512);
                acc[nt] = __builtin_amdgcn_mfma_f32_16x16x32_bf16(ahi, bhi, acc[nt], 0, 0, 0);
                acc[nt] = __builtin_amdgcn_mfma_f32_16x16x32_bf16(ahi, blo, acc[nt], 0, 0, 0);
                acc[nt] = __builtin_amdgcn_mfma_f32_16x16x32_bf16(alo, bhi, acc[nt], 0, 0, 0);
            }
        }
#pragma unroll
        for (int nt = 0; nt < 4; ++nt) {
            int col = nt * 16 + m;
#pragma unroll
            for (int r = 0; r < 4; ++r) {
                int orow = n0 + quad * 4 + r;
                if (orow < N) out[(size_t)orow * 64 + col] = __float2half(acc[nt][r]);
            }
        }
    }
    if (gv && blockIdx.x == 0 && threadIdx.x < 32) {
        int dd = dest[0];
        int q = threadIdx.x;
        float acc2 = bm1[q];
        for (int k = 0; k < 64; ++k)
            acc2 = fmaf(h[(size_t)dd * 64 + k], Wm1[(128 + k) * 32 + q], acc2);
        gv[q] = acc2;
    }
}

// 8 lanes per edge; hsd FP16: [n*64+0:32]=hs, [n*64+32:64]=hd
__global__ __launch_bounds__(256) void edge_mlp_kernel(
    const int* __restrict__ ei, const float2* __restrict__ ea,
    const __half* __restrict__ hsd, const float* __restrict__ gvec,
    const float* __restrict__ WrowA, const float* __restrict__ WrowB,
    const float* __restrict__ Wm2, const float* __restrict__ bm2,
    float* __restrict__ out, int E) {
    int tid = blockIdx.x * blockDim.x + threadIdx.x;
    int e = tid >> 3;
    int j = tid & 7;
    if (e >= E) return;
    int s = ei[e], d = ei[E + e];
    float2 eav = ea[e];
    const __half2* ps = (const __half2*)(hsd + (size_t)s * 64 + j * 4);
    const __half2* pd = (const __half2*)(hsd + (size_t)d * 64 + 32 + j * 4);
    float2 a01 = __half22float2(ps[0]), a23 = __half22float2(ps[1]);
    float2 b01 = __half22float2(pd[0]), b23 = __half22float2(pd[1]);
    float4 g = *(const float4*)(gvec + j * 4);
    float4 wa = *(const float4*)(WrowA + j * 4);
    float4 wb = *(const float4*)(WrowB + j * 4);
    float4 w2 = *(const float4*)(Wm2 + j * 4);
    float acc = 0.f, v;
    v = fmaf(eav.x, wa.x, fmaf(eav.y, wb.x, a01.x + b01.x + g.x)); v = fmaxf(v, 0.f); acc = fmaf(v, w2.x, acc);
    v = fmaf(eav.x, wa.y, fmaf(eav.y, wb.y, a01.y + b01.y + g.y)); v = fmaxf(v, 0.f); acc = fmaf(v, w2.y, acc);
    v = fmaf(eav.x, wa.z, fmaf(eav.y, wb.z, a23.x + b23.x + g.z)); v = fmaxf(v, 0.f); acc = fmaf(v, w2.z, acc);
    v = fmaf(eav.x, wa.w, fmaf(eav.y, wb.w, a23.y + b23.y + g.w)); v = fmaxf(v, 0.f); acc = fmaf(v, w2.w, acc);
    acc = dpp_add<0xB1>(acc);    // xor 1
    acc = dpp_add<0x4E>(acc);    // xor 2
    acc = dpp_add<0x141>(acc);   // xor 7 — closes the 8-group
    if (j == 0) out[e] = acc + bm2[0];
}

extern "C" void kernel_launch(void* const* d_in, const int* in_sizes, int n_in,
                              void* d_out, int out_size, void* d_ws, size_t ws_size,
                              hipStream_t stream) {
    const float* x     = (const float*)d_in[0];
    const int*   ei    = (const int*)d_in[1];
    const float* ea    = (const float*)d_in[2];
    const int*   dest  = (const int*)d_in[3];
    const float* W0    = (const float*)d_in[4];
    const float* b0    = (const float*)d_in[5];
    const float* We0   = (const float*)d_in[6];
    const float* att0  = (const float*)d_in[7];
    const float* bias0 = (const float*)d_in[8];
    const float* W1    = (const float*)d_in[9];
    const float* b1    = (const float*)d_in[10];
    const float* We1   = (const float*)d_in[11];
    const float* att1  = (const float*)d_in[12];
    const float* bias1 = (const float*)d_in[13];
    const float* Wm1   = (const float*)d_in[14];
    const float* bm1   = (const float*)d_in[15];
    const float* Wm2   = (const float*)d_in[16];
    const float* bm2   = (const float*)d_in[17];

    const int N = in_sizes[0] / 2;
    const int E = in_sizes[1] / 2;
    const int EP = E + N;
    const int nbuck = (N + 127) >> BSH;
    const int nchunk = (E + CH - 1) / CH;

    char* ws = (char*)d_ws;
    size_t off = 0;
    auto alloc = [&](size_t bytes) -> void* {
        void* p = ws + off;
        off += bytes;
        off = (off + 255) & ~(size_t)255;
        return p;
    };
    int*    bucket_cursor = (int*)alloc((size_t)nbuck * 4);
    int*    row_ptr       = (int*)alloc((size_t)(N + 1) * 4);
    size_t  slack_bytes   = (size_t)nbuck * CAP * 16;
    size_t  shared_bytes  = slack_bytes > (size_t)N * 128 ? slack_bytes : (size_t)N * 128;
    float4* staged        = (float4*)alloc(shared_bytes);   // also z16/hsd16 (N*64*2B)
    float4* recs          = (float4*)alloc((size_t)EP * 16);
    float4* wrec          = (float4*)alloc((size_t)EP * 16);
    float*  hbuf          = (float*)alloc((size_t)N * 64 * 4);
    float*  easum         = (float*)alloc(8);
    float*  gvec          = (float*)alloc(32 * 4);
    short*  BfW1          = (short*)alloc(8192 * 2);
    short*  BfWm          = (short*)alloc(8192 * 2);
    __half* z16           = (__half*)staged;  // staged dead before hagg_gemm writes
    __half* hsd16         = z16;              // z1 dead after layer-1 agg

    dim3 blk(256);
    setup_kernel<<<3, 512, 0, stream>>>(W1, Wm1, BfW1, BfWm, bucket_cursor, easum, nbuck);
    phaseA_kernel<<<nchunk, blk, (size_t)nbuck * 8, stream>>>(ei, (const float2*)ea,
                                                              bucket_cursor, easum,
                                                              staged, E, nbuck);
    phaseB_kernel<<<nbuck, blk, 0, stream>>>(staged, bucket_cursor, easum,
                                             row_ptr, recs, N, E, nbuck);
    wgt0_kernel<<<2048, blk, 0, stream>>>((const float2*)x, W0, b0, recs, We0, att0, wrec, EP);
    hagg_gemm_kernel<<<(N + 63) / 64, blk, 0, stream>>>(wrec, row_ptr, W0, b0, bias0,
                                                        BfW1, b1, z16, N);
    agg1_kernel<<<(N * 64 + 255) / 256, blk, 0, stream>>>(z16, row_ptr, recs,
                                                          We1, att1, bias1, hbuf, N);
    mfma_gemm64<<<(N + 63) / 64, blk, 0, stream>>>(hbuf, BfWm, hsd16, N,
                                                   Wm1, bm1, dest, gvec);
    edge_mlp_kernel<<<((size_t)E * 8 + 255) / 256, blk, 0, stream>>>(
        ei, (const float2*)ea, hsd16, gvec,
        Wm1 + 192 * 32, Wm1 + 193 * 32, Wm2, bm2, (float*)d_out, E);
}

// Round 16
// 268.687 us; speedup vs baseline: 1.0185x; 1.0185x over previous
//
#include <hip/hip_runtime.h>
#include <hip/hip_bf16.h>
#include <hip/hip_fp16.h>
#include <math.h>

// ---------------------------------------------------------------------------
// GATv2 policy net: 2x GATv2 layer (H=2, C=32, share_weights) + edge MLP.
// CSR build = slack-bucket counting sort (128 nodes/bucket, CAP=4096 slack):
//   phaseA appends E real edges into per-bucket slack runs; easum fused.
//   phaseB computes its own bucket prefix inline, makes row_ptr, synthesizes
//   selfloop records, places records -> recs (E+N).
// Layer 0: rank-2 decomposition (x is 2-dim): wgt0 (edge-parallel) -> wrec;
//   hagg_gemm fuses hagg0 + gemm1 (h0 lives only in LDS) -> z16 (fp16).
// Layer 1: agg1 fused attention+aggregation (R13 ILP-8 form — 4 restructure
//   attempts all regressed; this is the empirical optimum); z1 FP16.
// Cross-lane reduces use DPP (R12: ds_swizzle hops slower).
// Unnormalized softmax (clamp 60): exp cannot overflow; same math.
// ---------------------------------------------------------------------------

typedef __attribute__((ext_vector_type(8))) short short8;
typedef __attribute__((ext_vector_type(4))) float f32x4;

#define BSH 7               // 128 nodes per bucket
#define CAP 4096            // slack per bucket (mean 2048, sigma ~45)
#define CH 4096             // edges per block in phaseA

template <int IMM>
__device__ __forceinline__ float swz(float x) {
    return __int_as_float(__builtin_amdgcn_ds_swizzle(__float_as_int(x), IMM));
}

template <int CTRL>
__device__ __forceinline__ float dpp_add(float p) {
    int t = __builtin_amdgcn_update_dpp(0, __float_as_int(p), CTRL, 0xF, 0xF, true);
    return p + __int_as_float(t);
}

// sum over the 32 lanes of this head; result in all lanes (DPP + 1 swizzle).
__device__ __forceinline__ float head_reduce(float p) {
    p = dpp_add<0xB1>(p);     // xor 1
    p = dpp_add<0x4E>(p);     // xor 2
    p = dpp_add<0x141>(p);    // xor 7 (half mirror)
    p = dpp_add<0x140>(p);    // xor 15 (row mirror)
    p += swz<0x401F>(p);      // xor 16
    return p;
}

// truncating fp32 -> (hi, lo) bf16 split
__device__ __forceinline__ short2 bsplit(float x) {
    unsigned u = __float_as_uint(x);
    short hi = (short)(u >> 16);
    float hif = __uint_as_float(u & 0xFFFF0000u);
    short lo = (short)(__float_as_uint(x - hif) >> 16);
    return make_short2(hi, lo);
}

// ---- setup: blocks 0,1 = bfrag; block 2 = init cursors + easum --------------
__global__ __launch_bounds__(512) void setup_kernel(const float* __restrict__ W1,
                                                    const float* __restrict__ Wm1,
                                                    short* __restrict__ BfW1,
                                                    short* __restrict__ BfWm,
                                                    int* __restrict__ bucket_cursor,
                                                    float* __restrict__ easum, int nbuck) {
    if (blockIdx.x == 2) {
        for (int i = threadIdx.x; i < nbuck; i += 512) bucket_cursor[i] = i * CAP;
        if (threadIdx.x < 2) easum[threadIdx.x] = 0.f;
        return;
    }
    int snt = threadIdx.x >> 6;
    int lane = threadIdx.x & 63;
    int s = snt >> 2, nt = snt & 3;
    int col = nt * 16 + (lane & 15);
    short* Bf = blockIdx.x == 0 ? BfW1 : BfWm;
#pragma unroll
    for (int j = 0; j < 8; ++j) {
        int k = s * 32 + (lane >> 4) * 8 + j;
        float v;
        if (blockIdx.x == 0) {
            v = W1[k * 64 + col];
        } else {
            v = (col < 32) ? Wm1[k * 32 + col] : Wm1[(64 + k) * 32 + (col - 32)];
        }
        short2 t = bsplit(v);
        Bf[(snt * 2 + 0) * 512 + lane * 8 + j] = t.x;
        Bf[(snt * 2 + 1) * 512 + lane * 8 + j] = t.y;
    }
}

// ---- phaseA: append E edges into slack bucket runs; easum fused -------------
__global__ __launch_bounds__(256) void phaseA_kernel(const int* __restrict__ ei,
                                                     const float2* __restrict__ ea,
                                                     int* __restrict__ bucket_cursor,
                                                     float* __restrict__ easum,
                                                     float4* __restrict__ staged,
                                                     int E, int nbuck) {
    extern __shared__ int sm[];          // lcnt[nbuck] then lbase[nbuck]
    int* lcnt = sm;
    int* lbase = sm + nbuck;
    __shared__ float r0[4], r1[4];
    int tid = threadIdx.x;
    for (int i = tid; i < nbuck; i += 256) lcnt[i] = 0;
    __syncthreads();
    int base = blockIdx.x * CH;
    int end = min(base + CH, E);
    for (int i = base + tid; i < end; i += 256) {
        int d = ei[E + i];
        atomicAdd(&lcnt[d >> BSH], 1);
    }
    __syncthreads();
    for (int i = tid; i < nbuck; i += 256) {
        int c = lcnt[i];
        lbase[i] = c ? atomicAdd(&bucket_cursor[i], c) : 0;
        lcnt[i] = 0;
    }
    __syncthreads();
    float s0 = 0.f, s1 = 0.f;
    for (int i = base + tid; i < end; i += 256) {
        int s = ei[i], d = ei[E + i];
        float2 v = ea[i];
        s0 += v.x; s1 += v.y;
        int b = d >> BSH;
        int pos = lbase[b] + atomicAdd(&lcnt[b], 1);
        staged[pos] = make_float4(__int_as_float(s), v.x, v.y, __int_as_float(d));
    }
#pragma unroll
    for (int o = 32; o >= 1; o >>= 1) {
        s0 += __shfl_xor(s0, o);
        s1 += __shfl_xor(s1, o);
    }
    int wave = tid >> 6;
    if ((tid & 63) == 0) { r0[wave] = s0; r1[wave] = s1; }
    __syncthreads();
    if (tid == 0) {
        atomicAdd(&easum[0], r0[0] + r0[1] + r0[2] + r0[3]);
        atomicAdd(&easum[1], r1[0] + r1[1] + r1[2] + r1[3]);
    }
}

// ---- phaseB: inline bucket prefix; per-node count+scan -> row_ptr;
//      synth selfloop at first CSR slot; place records -----------------------
__global__ __launch_bounds__(256) void phaseB_kernel(const float4* __restrict__ staged,
                                                     const int* __restrict__ bucket_cursor,
                                                     const float* __restrict__ easum,
                                                     int* __restrict__ row_ptr,
                                                     float4* __restrict__ recs,
                                                     int N, int E, int nbuck) {
    __shared__ int cnt128[128];
    __shared__ int offs[128];
    __shared__ int psum[256];
    int b = blockIdx.x;
    int n0 = b << BSH;
    int tid = threadIdx.x;
    int local = 0;
    for (int j = tid; j < b; j += 256) local += bucket_cursor[j] - j * CAP;
    psum[tid] = local;
    if (tid < 128) cnt128[tid] = 0;
    __syncthreads();
    for (int st = 128; st > 0; st >>= 1) {
        if (tid < st) psum[tid] += psum[tid + st];
        __syncthreads();
    }
    int bbase = psum[0] + 128 * b;           // exclusive, incl selfloops
    int sbeg = b * CAP;
    int send = bucket_cursor[b];             // slack run end
    for (int i = sbeg + tid; i < send; i += 256) {
        int d = __float_as_int(staged[i].w);
        atomicAdd(&cnt128[d - n0], 1);
    }
    __syncthreads();
    int node = n0 + tid;
    int tot = 0;
    if (tid < 128) {
        tot = cnt128[tid] + ((node < N) ? 1 : 0);   // +1 selfloop
        offs[tid] = tot;
    }
    __syncthreads();
    for (int st = 1; st < 128; st <<= 1) {
        int v = 0;
        if (tid < 128) {
            v = offs[tid];
            if (tid >= st) v += offs[tid - st];
        }
        __syncthreads();
        if (tid < 128) offs[tid] = v;
        __syncthreads();
    }
    float inv = 1.f / (float)E;
    float m0 = easum[0] * inv, m1 = easum[1] * inv;
    if (tid < 128 && node < N) {
        int excl = bbase + offs[tid] - tot;
        row_ptr[node] = excl;
        recs[excl] = make_float4(__int_as_float(node), m0, m1, __int_as_float(node));
        offs[tid] = excl + 1;
    }
    if (b == nbuck - 1 && tid == 0) {
        int nodes = min(128, N - n0);
        row_ptr[N] = bbase + (send - sbeg) + nodes;
    }
    __syncthreads();
    for (int i = sbeg + tid; i < send; i += 256) {
        float4 r = staged[i];
        int d = __float_as_int(r.w);
        int pos = atomicAdd(&offs[d - n0], 1);
        recs[pos] = r;
    }
}

// ---- wgt0: edge-parallel layer-0 attention weights --------------------------
__global__ __launch_bounds__(256) void wgt0_kernel(const float2* __restrict__ x,
                                                   const float* __restrict__ W0,
                                                   const float* __restrict__ b0,
                                                   const float4* __restrict__ recs,
                                                   const float* __restrict__ We,
                                                   const float* __restrict__ att,
                                                   float4* __restrict__ wrec, int EP) {
    int lane = threadIdx.x & 63;
    int m = lane & 15, quad = lane >> 4;
    int c0 = quad * 8, c1 = 32 + c0;
    float w0a[8], w1a[8], ata[8], w0b[8], w1b[8], atb[8];
    float Wxa[8], Wya[8], bca[8], Wxb[8], Wyb[8], bcb[8];
#pragma unroll
    for (int j = 0; j < 8; ++j) {
        w0a[j] = We[c0 + j];  w1a[j] = We[64 + c0 + j];  ata[j] = att[c0 + j];
        w0b[j] = We[c1 + j];  w1b[j] = We[64 + c1 + j];  atb[j] = att[c1 + j];
        Wxa[j] = W0[c0 + j];  Wya[j] = W0[64 + c0 + j];  bca[j] = b0[c0 + j];
        Wxb[j] = W0[c1 + j];  Wyb[j] = W0[64 + c1 + j];  bcb[j] = b0[c1 + j];
    }
    int ntiles = (EP + 15) >> 4;
    int wid = (blockIdx.x * blockDim.x + threadIdx.x) >> 6;
    int nw = (gridDim.x * blockDim.x) >> 6;
    for (int t = wid; t < ntiles; t += nw) {
        int e = t * 16 + m;
        int ec = e < EP ? e : EP - 1;
        float4 r = recs[ec];
        int s = __float_as_int(r.x);
        int d = __float_as_int(r.w);
        float2 xs = x[s];
        float2 xd = x[d];
        float P0 = 0.f, P1 = 0.f;
#pragma unroll
        for (int j = 0; j < 8; ++j) {
            float zs = fmaf(xs.x, Wxa[j], fmaf(xs.y, Wya[j], bca[j]));
            float zd = fmaf(xd.x, Wxa[j], fmaf(xd.y, Wya[j], bca[j]));
            float t0 = zd + zs + fmaf(r.y, w0a[j], r.z * w1a[j]);
            t0 = fmaxf(t0, 0.2f * t0);
            P0 = fmaf(t0, ata[j], P0);
            float zs1 = fmaf(xs.x, Wxb[j], fmaf(xs.y, Wyb[j], bcb[j]));
            float zd1 = fmaf(xd.x, Wxb[j], fmaf(xd.y, Wyb[j], bcb[j]));
            float t1 = zd1 + zs1 + fmaf(r.y, w0b[j], r.z * w1b[j]);
            t1 = fmaxf(t1, 0.2f * t1);
            P1 = fmaf(t1, atb[j], P1);
        }
        P0 += swz<0x401F>(P0);             // quad pair (xor 16)
        P1 += swz<0x401F>(P1);
        P0 += __shfl_xor(P0, 32);          // cross-half (xor 32)
        P1 += __shfl_xor(P1, 32);
        float w0 = __expf(fminf(P0, 60.f));
        float w1 = __expf(fminf(P1, 60.f));
        if (lane < 16 && e < EP) wrec[e] = make_float4(w0, w1, xs.x, xs.y);
    }
}

// ---- hagg_gemm: fused layer-0 aggregation (rank-2) + gemm1 ------------------
__global__ __launch_bounds__(256) void hagg_gemm_kernel(
    const float4* __restrict__ wrec, const int* __restrict__ row_ptr,
    const float* __restrict__ W0, const float* __restrict__ b0,
    const float* __restrict__ bias, const short* __restrict__ Bf,
    const float* __restrict__ b1, __half* __restrict__ z16, int N) {
    __shared__ float hl[64 * 64];
    int wave = threadIdx.x >> 6;
    int lane = threadIdx.x & 63;
    int n0 = blockIdx.x * 64;
    float W0a = W0[lane], W0b = W0[64 + lane], b0c = b0[lane], bj0 = bias[lane];
    for (int t = 0; t < 16; ++t) {
        int n = n0 + wave * 16 + t;
        int row = wave * 16 + t;
        if (n >= N) { hl[row * 64 + lane] = 0.f; continue; }
        int beg = row_ptr[n], end = row_ptr[n + 1];
        float a0 = 0.f, a1 = 0.f, a2 = 0.f, c0 = 0.f, c1 = 0.f, c2 = 0.f;
        for (int i = beg + lane; i < end; i += 64) {
            float4 r = wrec[i];
            a0 += r.x; a1 = fmaf(r.x, r.z, a1); a2 = fmaf(r.x, r.w, a2);
            c0 += r.y; c1 = fmaf(r.y, r.z, c1); c2 = fmaf(r.y, r.w, c2);
        }
#pragma unroll
        for (int o = 32; o >= 1; o >>= 1) {
            a0 += __shfl_xor(a0, o); a1 += __shfl_xor(a1, o); a2 += __shfl_xor(a2, o);
            c0 += __shfl_xor(c0, o); c1 += __shfl_xor(c1, o); c2 += __shfl_xor(c2, o);
        }
        int head = lane >> 5;
        float l  = head ? c0 : a0;
        float Sx = head ? c1 : a1;
        float Sy = head ? c2 : a2;
        float num = fmaf(W0a, Sx, fmaf(W0b, Sy, b0c * l));
        float v = num / (l + 1e-16f) + bj0;
        v = (v > 0.f) ? v : expm1f(v);       // ELU
        hl[row * 64 + lane] = v;
    }
    __syncthreads();
    int m = lane & 15, quad = lane >> 4;
    int rowb = wave * 16 + m;
    f32x4 acc[4] = {{0.f, 0.f, 0.f, 0.f}, {0.f, 0.f, 0.f, 0.f},
                    {0.f, 0.f, 0.f, 0.f}, {0.f, 0.f, 0.f, 0.f}};
#pragma unroll
    for (int s = 0; s < 2; ++s) {
        const float* ap = hl + rowb * 64 + s * 32 + quad * 8;
        float4 a0 = *(const float4*)ap;
        float4 a1 = *(const float4*)(ap + 4);
        short8 ahi, alo;
        short2 t;
        t = bsplit(a0.x); ahi[0] = t.x; alo[0] = t.y;
        t = bsplit(a0.y); ahi[1] = t.x; alo[1] = t.y;
        t = bsplit(a0.z); ahi[2] = t.x; alo[2] = t.y;
        t = bsplit(a0.w); ahi[3] = t.x; alo[3] = t.y;
        t = bsplit(a1.x); ahi[4] = t.x; alo[4] = t.y;
        t = bsplit(a1.y); ahi[5] = t.x; alo[5] = t.y;
        t = bsplit(a1.z); ahi[6] = t.x; alo[6] = t.y;
        t = bsplit(a1.w); ahi[7] = t.x; alo[7] = t.y;
#pragma unroll
        for (int nt = 0; nt < 4; ++nt) {
            const short* bp = Bf + ((s * 4 + nt) * 2) * 512 + lane * 8;
            short8 bhi = *(const short8*)bp;
            short8 blo = *(const short8*)(bp + 512);
            acc[nt] = __builtin_amdgcn_mfma_f32_16x16x32_bf16(ahi, bhi, acc[nt], 0, 0, 0);
            acc[nt] = __builtin_amdgcn_mfma_f32_16x16x32_bf16(ahi, blo, acc[nt], 0, 0, 0);
            acc[nt] = __builtin_amdgcn_mfma_f32_16x16x32_bf16(alo, bhi, acc[nt], 0, 0, 0);
        }
    }
#pragma unroll
    for (int nt = 0; nt < 4; ++nt) {
        int col = nt * 16 + m;
        float bj = b1[col];
#pragma unroll
        for (int r = 0; r < 4; ++r) {
            int orow = n0 + wave * 16 + quad * 4 + r;
            if (orow < N) z16[(size_t)orow * 64 + col] = __float2half(acc[nt][r] + bj);
        }
    }
}

// ---- agg1: fused attention+aggregation, layer 1; z FP16 (R13 ILP-8 form) ----
__global__ __launch_bounds__(256) void agg1_kernel(
    const __half* __restrict__ z, const int* __restrict__ row_ptr,
    const float4* __restrict__ recs,
    const float* __restrict__ We, const float* __restrict__ att,
    const float* __restrict__ bias, float* __restrict__ hout, int N) {
    int gtid = blockIdx.x * blockDim.x + threadIdx.x;
    int n = gtid >> 6;
    if (n >= N) return;
    n = __builtin_amdgcn_readfirstlane(n);
    int lane = threadIdx.x & 63;

    float We0 = We[lane], We1 = We[64 + lane];
    float attj = att[lane];
    float zn = __half2float(z[(size_t)n * 64 + lane]);

    int beg = row_ptr[n], end = row_ptr[n + 1];
    float ll[4] = {0.f, 0.f, 0.f, 0.f};
    float aa[4] = {0.f, 0.f, 0.f, 0.f};
    int i = beg;
    for (; i + 8 <= end; i += 8) {
        float w[8], zs[8];
#pragma unroll
        for (int k = 0; k < 8; ++k) {
            float4 r = recs[i + k];
            int s = __builtin_amdgcn_readfirstlane(__float_as_int(r.x));
            float zv = __half2float(z[(size_t)s * 64 + lane]);
            float sj = zn + zv + fmaf(r.y, We0, r.z * We1);
            sj = fmaxf(sj, 0.2f * sj);
            float alpha = head_reduce(sj * attj);
            w[k] = __expf(fminf(alpha, 60.f));
            zs[k] = zv;
        }
#pragma unroll
        for (int k = 0; k < 8; ++k) {
            ll[k & 3] += w[k];
            aa[k & 3] = fmaf(w[k], zs[k], aa[k & 3]);
        }
    }
    for (; i < end; ++i) {
        float4 r = recs[i];
        int s = __builtin_amdgcn_readfirstlane(__float_as_int(r.x));
        float zv = __half2float(z[(size_t)s * 64 + lane]);
        float sj = zn + zv + fmaf(r.y, We0, r.z * We1);
        sj = fmaxf(sj, 0.2f * sj);
        float alpha = head_reduce(sj * attj);
        float w = __expf(fminf(alpha, 60.f));
        ll[0] += w;
        aa[0] = fmaf(w, zv, aa[0]);
    }
    float l = (ll[0] + ll[1]) + (ll[2] + ll[3]);
    float a = (aa[0] + aa[1]) + (aa[2] + aa[3]);
    float v = a / (l + 1e-16f) + bias[lane];
    v = (v > 0.f) ? v : expm1f(v);
    hout[(size_t)n * 64 + lane] = v;
}

// ---- out[N x 64] = h[N x 64] @ B[64 x 64], split-bf16 MFMA, fp16 out --------
// gvec fold: block 0 threads 0-31 also compute the goal vector.
__global__ __launch_bounds__(256) void mfma_gemm64(const float* __restrict__ h,
                                                   const short* __restrict__ Bf,
                                                   __half* __restrict__ out, int N,
                                                   const float* __restrict__ Wm1,
                                                   const float* __restrict__ bm1,
                                                   const int* __restrict__ dest,
                                                   float* __restrict__ gv) {
    int wave = threadIdx.x >> 6;
    int lane = threadIdx.x & 63;
    int n0 = blockIdx.x * 64 + wave * 16;
    if (n0 < N) {
        int m = lane & 15, quad = lane >> 4;
        int arow = n0 + m;
        if (arow > N - 1) arow = N - 1;
        f32x4 acc[4] = {{0.f, 0.f, 0.f, 0.f}, {0.f, 0.f, 0.f, 0.f},
                        {0.f, 0.f, 0.f, 0.f}, {0.f, 0.f, 0.f, 0.f}};
#pragma unroll
        for (int s = 0; s < 2; ++s) {
            const float* ap = h + (size_t)arow * 64 + s * 32 + quad * 8;
            float4 a0 = *(const float4*)ap;
            float4 a1 = *(const float4*)(ap + 4);
            short8 ahi, alo;
            short2 t;
            t = bsplit(a0.x); ahi[0] = t.x; alo[0] = t.y;
            t = bsplit(a0.y); ahi[1] = t.x; alo[1] = t.y;
            t = bsplit(a0.z); ahi[2] = t.x; alo[2] = t.y;
            t = bsplit(a0.w); ahi[3] = t.x; alo[3] = t.y;
            t = bsplit(a1.x); ahi[4] = t.x; alo[4] = t.y;
            t = bsplit(a1.y); ahi[5] = t.x; alo[5] = t.y;
            t = bsplit(a1.z); ahi[6] = t.x; alo[6] = t.y;
            t = bsplit(a1.w); ahi[7] = t.x; alo[7] = t.y;
#pragma unroll
            for (int nt = 0; nt < 4; ++nt) {
                const short* bp = Bf + ((s * 4 + nt) * 2) * 512 + lane * 8;
                short8 bhi = *(const short8*)bp;
                short8 blo = *(const short8*)(bp + 512);
                acc[nt] = __builtin_amdgcn_mfma_f32_16x16x32_bf16(ahi, bhi, acc[nt], 0, 0, 0);
                acc[nt] = __builtin_amdgcn_mfma_f32_16x16x32_bf16(ahi, blo, acc[nt], 0, 0, 0);
                acc[nt] = __builtin_amdgcn_mfma_f32_16x16x32_bf16(alo, bhi, acc[nt], 0, 0, 0);
            }
        }
#pragma unroll
        for (int nt = 0; nt < 4; ++nt) {
            int col = nt * 16 + m;
#pragma unroll
            for (int r = 0; r < 4; ++r) {
                int orow = n0 + quad * 4 + r;
                if (orow < N) out[(size_t)orow * 64 + col] = __float2half(acc[nt][r]);
            }
        }
    }
    if (gv && blockIdx.x == 0 && threadIdx.x < 32) {
        int dd = dest[0];
        int q = threadIdx.x;
        float acc2 = bm1[q];
        for (int k = 0; k < 64; ++k)
            acc2 = fmaf(h[(size_t)dd * 64 + k], Wm1[(128 + k) * 32 + q], acc2);
        gv[q] = acc2;
    }
}

// 8 lanes per edge; hsd FP16: [n*64+0:32]=hs, [n*64+32:64]=hd
__global__ __launch_bounds__(256) void edge_mlp_kernel(
    const int* __restrict__ ei, const float2* __restrict__ ea,
    const __half* __restrict__ hsd, const float* __restrict__ gvec,
    const float* __restrict__ WrowA, const float* __restrict__ WrowB,
    const float* __restrict__ Wm2, const float* __restrict__ bm2,
    float* __restrict__ out, int E) {
    int tid = blockIdx.x * blockDim.x + threadIdx.x;
    int e = tid >> 3;
    int j = tid & 7;
    if (e >= E) return;
    int s = ei[e], d = ei[E + e];
    float2 eav = ea[e];
    const __half2* ps = (const __half2*)(hsd + (size_t)s * 64 + j * 4);
    const __half2* pd = (const __half2*)(hsd + (size_t)d * 64 + 32 + j * 4);
    float2 a01 = __half22float2(ps[0]), a23 = __half22float2(ps[1]);
    float2 b01 = __half22float2(pd[0]), b23 = __half22float2(pd[1]);
    float4 g = *(const float4*)(gvec + j * 4);
    float4 wa = *(const float4*)(WrowA + j * 4);
    float4 wb = *(const float4*)(WrowB + j * 4);
    float4 w2 = *(const float4*)(Wm2 + j * 4);
    float acc = 0.f, v;
    v = fmaf(eav.x, wa.x, fmaf(eav.y, wb.x, a01.x + b01.x + g.x)); v = fmaxf(v, 0.f); acc = fmaf(v, w2.x, acc);
    v = fmaf(eav.x, wa.y, fmaf(eav.y, wb.y, a01.y + b01.y + g.y)); v = fmaxf(v, 0.f); acc = fmaf(v, w2.y, acc);
    v = fmaf(eav.x, wa.z, fmaf(eav.y, wb.z, a23.x + b23.x + g.z)); v = fmaxf(v, 0.f); acc = fmaf(v, w2.z, acc);
    v = fmaf(eav.x, wa.w, fmaf(eav.y, wb.w, a23.y + b23.y + g.w)); v = fmaxf(v, 0.f); acc = fmaf(v, w2.w, acc);
    acc = dpp_add<0xB1>(acc);    // xor 1
    acc = dpp_add<0x4E>(acc);    // xor 2
    acc = dpp_add<0x141>(acc);   // xor 7 — closes the 8-group
    if (j == 0) out[e] = acc + bm2[0];
}

extern "C" void kernel_launch(void* const* d_in, const int* in_sizes, int n_in,
                              void* d_out, int out_size, void* d_ws, size_t ws_size,
                              hipStream_t stream) {
    const float* x     = (const float*)d_in[0];
    const int*   ei    = (const int*)d_in[1];
    const float* ea    = (const float*)d_in[2];
    const int*   dest  = (const int*)d_in[3];
    const float* W0    = (const float*)d_in[4];
    const float* b0    = (const float*)d_in[5];
    const float* We0   = (const float*)d_in[6];
    const float* att0  = (const float*)d_in[7];
    const float* bias0 = (const float*)d_in[8];
    const float* W1    = (const float*)d_in[9];
    const float* b1    = (const float*)d_in[10];
    const float* We1   = (const float*)d_in[11];
    const float* att1  = (const float*)d_in[12];
    const float* bias1 = (const float*)d_in[13];
    const float* Wm1   = (const float*)d_in[14];
    const float* bm1   = (const float*)d_in[15];
    const float* Wm2   = (const float*)d_in[16];
    const float* bm2   = (const float*)d_in[17];

    const int N = in_sizes[0] / 2;
    const int E = in_sizes[1] / 2;
    const int EP = E + N;
    const int nbuck = (N + 127) >> BSH;
    const int nchunk = (E + CH - 1) / CH;

    char* ws = (char*)d_ws;
    size_t off = 0;
    auto alloc = [&](size_t bytes) -> void* {
        void* p = ws + off;
        off += bytes;
        off = (off + 255) & ~(size_t)255;
        return p;
    };
    int*    bucket_cursor = (int*)alloc((size_t)nbuck * 4);
    int*    row_ptr       = (int*)alloc((size_t)(N + 1) * 4);
    size_t  slack_bytes   = (size_t)nbuck * CAP * 16;
    size_t  shared_bytes  = slack_bytes > (size_t)N * 128 ? slack_bytes : (size_t)N * 128;
    float4* staged        = (float4*)alloc(shared_bytes);   // also z16/hsd16 (N*64*2B)
    float4* recs          = (float4*)alloc((size_t)EP * 16);
    float4* wrec          = (float4*)alloc((size_t)EP * 16);
    float*  hbuf          = (float*)alloc((size_t)N * 64 * 4);
    float*  easum         = (float*)alloc(8);
    float*  gvec          = (float*)alloc(32 * 4);
    short*  BfW1          = (short*)alloc(8192 * 2);
    short*  BfWm          = (short*)alloc(8192 * 2);
    __half* z16           = (__half*)staged;  // staged dead before hagg_gemm writes
    __half* hsd16         = z16;              // z1 dead after layer-1 agg

    dim3 blk(256);
    setup_kernel<<<3, 512, 0, stream>>>(W1, Wm1, BfW1, BfWm, bucket_cursor, easum, nbuck);
    phaseA_kernel<<<nchunk, blk, (size_t)nbuck * 8, stream>>>(ei, (const float2*)ea,
                                                              bucket_cursor, easum,
                                                              staged, E, nbuck);
    phaseB_kernel<<<nbuck, blk, 0, stream>>>(staged, bucket_cursor, easum,
                                             row_ptr, recs, N, E, nbuck);
    wgt0_kernel<<<2048, blk, 0, stream>>>((const float2*)x, W0, b0, recs, We0, att0, wrec, EP);
    hagg_gemm_kernel<<<(N + 63) / 64, blk, 0, stream>>>(wrec, row_ptr, W0, b0, bias0,
                                                        BfW1, b1, z16, N);
    agg1_kernel<<<(N * 64 + 255) / 256, blk, 0, stream>>>(z16, row_ptr, recs,
                                                          We1, att1, bias1, hbuf, N);
    mfma_gemm64<<<(N + 63) / 64, blk, 0, stream>>>(hbuf, BfWm, hsd16, N,
                                                   Wm1, bm1, dest, gvec);
    edge_mlp_kernel<<<((size_t)E * 8 + 255) / 256, blk, 0, stream>>>(
        ei, (const float2*)ea, hsd16, gvec,
        Wm1 + 192 * 32, Wm1 + 193 * 32, Wm2, bm2, (float*)d_out, E);
}

// Round 17
// 263.900 us; speedup vs baseline: 1.0370x; 1.0181x over previous
//
#include <hip/hip_runtime.h>
#include <hip/hip_bf16.h>
#include <hip/hip_fp16.h>
#include <math.h>

// ---------------------------------------------------------------------------
// GATv2 policy net: 2x GATv2 layer (H=2, C=32, share_weights) + edge MLP.
// CSR build = slack-bucket counting sort (128 nodes/bucket, CAP=4096 slack).
// Layer 0: rank-2 decomposition; wgt0 (edge-parallel) -> wrec; hagg_gemm
//   fuses layer-0 aggregation + gemm1 (h0 in LDS only) -> z16 (fp16).
// Layer 1: agg1 channel-paired: lane m owns channels (2m,2m+1) (same head;
//   16-lane DPP rows = head groups), each 32-lane half processes one edge
//   -> 2 edges per wave pass; 4-hop reduce; 1 exp per 4 alphas; halves the
//   per-edge fixed overhead vs lane=channel. fp32 math unchanged.
// Cross-lane reduces use DPP (R12: ds_swizzle hops slower).
// Unnormalized softmax (clamp 60): exp cannot overflow; same math.
// ---------------------------------------------------------------------------

typedef __attribute__((ext_vector_type(8))) short short8;
typedef __attribute__((ext_vector_type(4))) float f32x4;

#define BSH 7               // 128 nodes per bucket
#define CAP 4096            // slack per bucket (mean 2048, sigma ~45)
#define CH 4096             // edges per block in phaseA

template <int IMM>
__device__ __forceinline__ float swz(float x) {
    return __int_as_float(__builtin_amdgcn_ds_swizzle(__float_as_int(x), IMM));
}

template <int CTRL>
__device__ __forceinline__ float dpp_add(float p) {
    int t = __builtin_amdgcn_update_dpp(0, __float_as_int(p), CTRL, 0xF, 0xF, true);
    return p + __int_as_float(t);
}

// truncating fp32 -> (hi, lo) bf16 split
__device__ __forceinline__ short2 bsplit(float x) {
    unsigned u = __float_as_uint(x);
    short hi = (short)(u >> 16);
    float hif = __uint_as_float(u & 0xFFFF0000u);
    short lo = (short)(__float_as_uint(x - hif) >> 16);
    return make_short2(hi, lo);
}

// ---- setup: blocks 0,1 = bfrag; block 2 = init cursors + easum --------------
__global__ __launch_bounds__(512) void setup_kernel(const float* __restrict__ W1,
                                                    const float* __restrict__ Wm1,
                                                    short* __restrict__ BfW1,
                                                    short* __restrict__ BfWm,
                                                    int* __restrict__ bucket_cursor,
                                                    float* __restrict__ easum, int nbuck) {
    if (blockIdx.x == 2) {
        for (int i = threadIdx.x; i < nbuck; i += 512) bucket_cursor[i] = i * CAP;
        if (threadIdx.x < 2) easum[threadIdx.x] = 0.f;
        return;
    }
    int snt = threadIdx.x >> 6;
    int lane = threadIdx.x & 63;
    int s = snt >> 2, nt = snt & 3;
    int col = nt * 16 + (lane & 15);
    short* Bf = blockIdx.x == 0 ? BfW1 : BfWm;
#pragma unroll
    for (int j = 0; j < 8; ++j) {
        int k = s * 32 + (lane >> 4) * 8 + j;
        float v;
        if (blockIdx.x == 0) {
            v = W1[k * 64 + col];
        } else {
            v = (col < 32) ? Wm1[k * 32 + col] : Wm1[(64 + k) * 32 + (col - 32)];
        }
        short2 t = bsplit(v);
        Bf[(snt * 2 + 0) * 512 + lane * 8 + j] = t.x;
        Bf[(snt * 2 + 1) * 512 + lane * 8 + j] = t.y;
    }
}

// ---- phaseA: append E edges into slack bucket runs; easum fused -------------
__global__ __launch_bounds__(256) void phaseA_kernel(const int* __restrict__ ei,
                                                     const float2* __restrict__ ea,
                                                     int* __restrict__ bucket_cursor,
                                                     float* __restrict__ easum,
                                                     float4* __restrict__ staged,
                                                     int E, int nbuck) {
    extern __shared__ int sm[];          // lcnt[nbuck] then lbase[nbuck]
    int* lcnt = sm;
    int* lbase = sm + nbuck;
    __shared__ float r0[4], r1[4];
    int tid = threadIdx.x;
    for (int i = tid; i < nbuck; i += 256) lcnt[i] = 0;
    __syncthreads();
    int base = blockIdx.x * CH;
    int end = min(base + CH, E);
    for (int i = base + tid; i < end; i += 256) {
        int d = ei[E + i];
        atomicAdd(&lcnt[d >> BSH], 1);
    }
    __syncthreads();
    for (int i = tid; i < nbuck; i += 256) {
        int c = lcnt[i];
        lbase[i] = c ? atomicAdd(&bucket_cursor[i], c) : 0;
        lcnt[i] = 0;
    }
    __syncthreads();
    float s0 = 0.f, s1 = 0.f;
    for (int i = base + tid; i < end; i += 256) {
        int s = ei[i], d = ei[E + i];
        float2 v = ea[i];
        s0 += v.x; s1 += v.y;
        int b = d >> BSH;
        int pos = lbase[b] + atomicAdd(&lcnt[b], 1);
        staged[pos] = make_float4(__int_as_float(s), v.x, v.y, __int_as_float(d));
    }
#pragma unroll
    for (int o = 32; o >= 1; o >>= 1) {
        s0 += __shfl_xor(s0, o);
        s1 += __shfl_xor(s1, o);
    }
    int wave = tid >> 6;
    if ((tid & 63) == 0) { r0[wave] = s0; r1[wave] = s1; }
    __syncthreads();
    if (tid == 0) {
        atomicAdd(&easum[0], r0[0] + r0[1] + r0[2] + r0[3]);
        atomicAdd(&easum[1], r1[0] + r1[1] + r1[2] + r1[3]);
    }
}

// ---- phaseB: inline bucket prefix; per-node count+scan -> row_ptr;
//      synth selfloop at first CSR slot; place records -----------------------
__global__ __launch_bounds__(256) void phaseB_kernel(const float4* __restrict__ staged,
                                                     const int* __restrict__ bucket_cursor,
                                                     const float* __restrict__ easum,
                                                     int* __restrict__ row_ptr,
                                                     float4* __restrict__ recs,
                                                     int N, int E, int nbuck) {
    __shared__ int cnt128[128];
    __shared__ int offs[128];
    __shared__ int psum[256];
    int b = blockIdx.x;
    int n0 = b << BSH;
    int tid = threadIdx.x;
    int local = 0;
    for (int j = tid; j < b; j += 256) local += bucket_cursor[j] - j * CAP;
    psum[tid] = local;
    if (tid < 128) cnt128[tid] = 0;
    __syncthreads();
    for (int st = 128; st > 0; st >>= 1) {
        if (tid < st) psum[tid] += psum[tid + st];
        __syncthreads();
    }
    int bbase = psum[0] + 128 * b;           // exclusive, incl selfloops
    int sbeg = b * CAP;
    int send = bucket_cursor[b];             // slack run end
    for (int i = sbeg + tid; i < send; i += 256) {
        int d = __float_as_int(staged[i].w);
        atomicAdd(&cnt128[d - n0], 1);
    }
    __syncthreads();
    int node = n0 + tid;
    int tot = 0;
    if (tid < 128) {
        tot = cnt128[tid] + ((node < N) ? 1 : 0);   // +1 selfloop
        offs[tid] = tot;
    }
    __syncthreads();
    for (int st = 1; st < 128; st <<= 1) {
        int v = 0;
        if (tid < 128) {
            v = offs[tid];
            if (tid >= st) v += offs[tid - st];
        }
        __syncthreads();
        if (tid < 128) offs[tid] = v;
        __syncthreads();
    }
    float inv = 1.f / (float)E;
    float m0 = easum[0] * inv, m1 = easum[1] * inv;
    if (tid < 128 && node < N) {
        int excl = bbase + offs[tid] - tot;
        row_ptr[node] = excl;
        recs[excl] = make_float4(__int_as_float(node), m0, m1, __int_as_float(node));
        offs[tid] = excl + 1;
    }
    if (b == nbuck - 1 && tid == 0) {
        int nodes = min(128, N - n0);
        row_ptr[N] = bbase + (send - sbeg) + nodes;
    }
    __syncthreads();
    for (int i = sbeg + tid; i < send; i += 256) {
        float4 r = staged[i];
        int d = __float_as_int(r.w);
        int pos = atomicAdd(&offs[d - n0], 1);
        recs[pos] = r;
    }
}

// ---- wgt0: edge-parallel layer-0 attention weights --------------------------
__global__ __launch_bounds__(256) void wgt0_kernel(const float2* __restrict__ x,
                                                   const float* __restrict__ W0,
                                                   const float* __restrict__ b0,
                                                   const float4* __restrict__ recs,
                                                   const float* __restrict__ We,
                                                   const float* __restrict__ att,
                                                   float4* __restrict__ wrec, int EP) {
    int lane = threadIdx.x & 63;
    int m = lane & 15, quad = lane >> 4;
    int c0 = quad * 8, c1 = 32 + c0;
    float w0a[8], w1a[8], ata[8], w0b[8], w1b[8], atb[8];
    float Wxa[8], Wya[8], bca[8], Wxb[8], Wyb[8], bcb[8];
#pragma unroll
    for (int j = 0; j < 8; ++j) {
        w0a[j] = We[c0 + j];  w1a[j] = We[64 + c0 + j];  ata[j] = att[c0 + j];
        w0b[j] = We[c1 + j];  w1b[j] = We[64 + c1 + j];  atb[j] = att[c1 + j];
        Wxa[j] = W0[c0 + j];  Wya[j] = W0[64 + c0 + j];  bca[j] = b0[c0 + j];
        Wxb[j] = W0[c1 + j];  Wyb[j] = W0[64 + c1 + j];  bcb[j] = b0[c1 + j];
    }
    int ntiles = (EP + 15) >> 4;
    int wid = (blockIdx.x * blockDim.x + threadIdx.x) >> 6;
    int nw = (gridDim.x * blockDim.x) >> 6;
    for (int t = wid; t < ntiles; t += nw) {
        int e = t * 16 + m;
        int ec = e < EP ? e : EP - 1;
        float4 r = recs[ec];
        int s = __float_as_int(r.x);
        int d = __float_as_int(r.w);
        float2 xs = x[s];
        float2 xd = x[d];
        float P0 = 0.f, P1 = 0.f;
#pragma unroll
        for (int j = 0; j < 8; ++j) {
            float zs = fmaf(xs.x, Wxa[j], fmaf(xs.y, Wya[j], bca[j]));
            float zd = fmaf(xd.x, Wxa[j], fmaf(xd.y, Wya[j], bca[j]));
            float t0 = zd + zs + fmaf(r.y, w0a[j], r.z * w1a[j]);
            t0 = fmaxf(t0, 0.2f * t0);
            P0 = fmaf(t0, ata[j], P0);
            float zs1 = fmaf(xs.x, Wxb[j], fmaf(xs.y, Wyb[j], bcb[j]));
            float zd1 = fmaf(xd.x, Wxb[j], fmaf(xd.y, Wyb[j], bcb[j]));
            float t1 = zd1 + zs1 + fmaf(r.y, w0b[j], r.z * w1b[j]);
            t1 = fmaxf(t1, 0.2f * t1);
            P1 = fmaf(t1, atb[j], P1);
        }
        P0 += swz<0x401F>(P0);             // quad pair (xor 16)
        P1 += swz<0x401F>(P1);
        P0 += __shfl_xor(P0, 32);          // cross-half (xor 32)
        P1 += __shfl_xor(P1, 32);
        float w0 = __expf(fminf(P0, 60.f));
        float w1 = __expf(fminf(P1, 60.f));
        if (lane < 16 && e < EP) wrec[e] = make_float4(w0, w1, xs.x, xs.y);
    }
}

// ---- hagg_gemm: fused layer-0 aggregation (rank-2) + gemm1 ------------------
__global__ __launch_bounds__(256) void hagg_gemm_kernel(
    const float4* __restrict__ wrec, const int* __restrict__ row_ptr,
    const float* __restrict__ W0, const float* __restrict__ b0,
    const float* __restrict__ bias, const short* __restrict__ Bf,
    const float* __restrict__ b1, __half* __restrict__ z16, int N) {
    __shared__ float hl[64 * 64];
    int wave = threadIdx.x >> 6;
    int lane = threadIdx.x & 63;
    int n0 = blockIdx.x * 64;
    float W0a = W0[lane], W0b = W0[64 + lane], b0c = b0[lane], bj0 = bias[lane];
    for (int t = 0; t < 16; ++t) {
        int n = n0 + wave * 16 + t;
        int row = wave * 16 + t;
        if (n >= N) { hl[row * 64 + lane] = 0.f; continue; }
        int beg = row_ptr[n], end = row_ptr[n + 1];
        float a0 = 0.f, a1 = 0.f, a2 = 0.f, c0 = 0.f, c1 = 0.f, c2 = 0.f;
        for (int i = beg + lane; i < end; i += 64) {
            float4 r = wrec[i];
            a0 += r.x; a1 = fmaf(r.x, r.z, a1); a2 = fmaf(r.x, r.w, a2);
            c0 += r.y; c1 = fmaf(r.y, r.z, c1); c2 = fmaf(r.y, r.w, c2);
        }
#pragma unroll
        for (int o = 32; o >= 1; o >>= 1) {
            a0 += __shfl_xor(a0, o); a1 += __shfl_xor(a1, o); a2 += __shfl_xor(a2, o);
            c0 += __shfl_xor(c0, o); c1 += __shfl_xor(c1, o); c2 += __shfl_xor(c2, o);
        }
        int head = lane >> 5;
        float l  = head ? c0 : a0;
        float Sx = head ? c1 : a1;
        float Sy = head ? c2 : a2;
        float num = fmaf(W0a, Sx, fmaf(W0b, Sy, b0c * l));
        float v = num / (l + 1e-16f) + bj0;
        v = (v > 0.f) ? v : expm1f(v);       // ELU
        hl[row * 64 + lane] = v;
    }
    __syncthreads();
    int m = lane & 15, quad = lane >> 4;
    int rowb = wave * 16 + m;
    f32x4 acc[4] = {{0.f, 0.f, 0.f, 0.f}, {0.f, 0.f, 0.f, 0.f},
                    {0.f, 0.f, 0.f, 0.f}, {0.f, 0.f, 0.f, 0.f}};
#pragma unroll
    for (int s = 0; s < 2; ++s) {
        const float* ap = hl + rowb * 64 + s * 32 + quad * 8;
        float4 a0 = *(const float4*)ap;
        float4 a1 = *(const float4*)(ap + 4);
        short8 ahi, alo;
        short2 t;
        t = bsplit(a0.x); ahi[0] = t.x; alo[0] = t.y;
        t = bsplit(a0.y); ahi[1] = t.x; alo[1] = t.y;
        t = bsplit(a0.z); ahi[2] = t.x; alo[2] = t.y;
        t = bsplit(a0.w); ahi[3] = t.x; alo[3] = t.y;
        t = bsplit(a1.x); ahi[4] = t.x; alo[4] = t.y;
        t = bsplit(a1.y); ahi[5] = t.x; alo[5] = t.y;
        t = bsplit(a1.z); ahi[6] = t.x; alo[6] = t.y;
        t = bsplit(a1.w); ahi[7] = t.x; alo[7] = t.y;
#pragma unroll
        for (int nt = 0; nt < 4; ++nt) {
            const short* bp = Bf + ((s * 4 + nt) * 2) * 512 + lane * 8;
            short8 bhi = *(const short8*)bp;
            short8 blo = *(const short8*)(bp + 512);
            acc[nt] = __builtin_amdgcn_mfma_f32_16x16x32_bf16(ahi, bhi, acc[nt], 0, 0, 0);
            acc[nt] = __builtin_amdgcn_mfma_f32_16x16x32_bf16(ahi, blo, acc[nt], 0, 0, 0);
            acc[nt] = __builtin_amdgcn_mfma_f32_16x16x32_bf16(alo, bhi, acc[nt], 0, 0, 0);
        }
    }
#pragma unroll
    for (int nt = 0; nt < 4; ++nt) {
        int col = nt * 16 + m;
        float bj = b1[col];
#pragma unroll
        for (int r = 0; r < 4; ++r) {
            int orow = n0 + wave * 16 + quad * 4 + r;
            if (orow < N) z16[(size_t)orow * 64 + col] = __float2half(acc[nt][r] + bj);
        }
    }
}

// ---- agg1: channel-paired fused attention+aggregation, layer 1; z FP16 ------
// lane m in [0,32) owns channels (2m, 2m+1) — same head (m<16: h0, else h1);
// 16-lane DPP rows = head groups. Half-wave = one edge; 2 edges per pass.
__global__ __launch_bounds__(256) void agg1_kernel(
    const __half* __restrict__ z, const int* __restrict__ row_ptr,
    const float4* __restrict__ recs,
    const float* __restrict__ We, const float* __restrict__ att,
    const float* __restrict__ bias, float* __restrict__ hout, int N) {
    int gtid = blockIdx.x * blockDim.x + threadIdx.x;
    int n = gtid >> 6;
    if (n >= N) return;
    n = __builtin_amdgcn_readfirstlane(n);
    int lane = threadIdx.x & 63;
    int half = lane >> 5;          // which edge of the pair
    int c = (lane & 31) * 2;       // channel pair (c, c+1)

    float We0a = We[c],      We0b = We[c + 1];
    float We1a = We[64 + c], We1b = We[64 + c + 1];
    float atta = att[c],     attb = att[c + 1];
    float2 znf = __half22float2(*(const __half2*)(z + (size_t)n * 64 + c));

    int beg = row_ptr[n], end = row_ptr[n + 1];
    float ll[4] = {0.f, 0.f, 0.f, 0.f};
    float a0[4] = {0.f, 0.f, 0.f, 0.f};
    float a1[4] = {0.f, 0.f, 0.f, 0.f};
    for (int i = beg; i < end; i += 8) {
        float w[4]; float2 zs[4];
#pragma unroll
        for (int k = 0; k < 4; ++k) {
            int idx = i + 2 * k + half;
            int idc = idx < end ? idx : end - 1;
            float4 r = recs[idc];
            int s = __float_as_int(r.x);
            zs[k] = __half22float2(*(const __half2*)(z + (size_t)s * 64 + c));
            float sj0 = znf.x + zs[k].x + fmaf(r.y, We0a, r.z * We1a);
            float sj1 = znf.y + zs[k].y + fmaf(r.y, We0b, r.z * We1b);
            sj0 = fmaxf(sj0, 0.2f * sj0);          // leaky_relu(0.2)
            sj1 = fmaxf(sj1, 0.2f * sj1);
            float p = fmaf(sj0, atta, sj1 * attb); // pair partial
            p = dpp_add<0xB1>(p);                  // xor 1
            p = dpp_add<0x4E>(p);                  // xor 2
            p = dpp_add<0x141>(p);                 // xor 7 (half mirror)
            p = dpp_add<0x140>(p);                 // xor 15 -> 16-lane head sum
            float ww = __expf(fminf(p, 60.f));
            w[k] = (idx < end) ? ww : 0.f;         // mask clamped tail
        }
#pragma unroll
        for (int k = 0; k < 4; ++k) {
            ll[k] += w[k];
            a0[k] = fmaf(w[k], zs[k].x, a0[k]);
            a1[k] = fmaf(w[k], zs[k].y, a1[k]);
        }
    }
    float l  = (ll[0] + ll[1]) + (ll[2] + ll[3]);
    float s0 = (a0[0] + a0[1]) + (a0[2] + a0[3]);
    float s1 = (a1[0] + a1[1]) + (a1[2] + a1[3]);
    // combine the two half-wave edge subsets
    l  += __shfl_xor(l, 32);
    s0 += __shfl_xor(s0, 32);
    s1 += __shfl_xor(s1, 32);
    float inv = 1.f / (l + 1e-16f);
    float v0 = s0 * inv + bias[c];
    float v1 = s1 * inv + bias[c + 1];
    v0 = (v0 > 0.f) ? v0 : expm1f(v0);             // ELU
    v1 = (v1 > 0.f) ? v1 : expm1f(v1);
    *(float2*)(hout + (size_t)n * 64 + c) = make_float2(v0, v1);
}

// ---- out[N x 64] = h[N x 64] @ B[64 x 64], split-bf16 MFMA, fp16 out --------
// gvec fold: block 0 threads 0-31 also compute the goal vector.
__global__ __launch_bounds__(256) void mfma_gemm64(const float* __restrict__ h,
                                                   const short* __restrict__ Bf,
                                                   __half* __restrict__ out, int N,
                                                   const float* __restrict__ Wm1,
                                                   const float* __restrict__ bm1,
                                                   const int* __restrict__ dest,
                                                   float* __restrict__ gv) {
    int wave = threadIdx.x >> 6;
    int lane = threadIdx.x & 63;
    int n0 = blockIdx.x * 64 + wave * 16;
    if (n0 < N) {
        int m = lane & 15, quad = lane >> 4;
        int arow = n0 + m;
        if (arow > N - 1) arow = N - 1;
        f32x4 acc[4] = {{0.f, 0.f, 0.f, 0.f}, {0.f, 0.f, 0.f, 0.f},
                        {0.f, 0.f, 0.f, 0.f}, {0.f, 0.f, 0.f, 0.f}};
#pragma unroll
        for (int s = 0; s < 2; ++s) {
            const float* ap = h + (size_t)arow * 64 + s * 32 + quad * 8;
            float4 a0 = *(const float4*)ap;
            float4 a1 = *(const float4*)(ap + 4);
            short8 ahi, alo;
            short2 t;
            t = bsplit(a0.x); ahi[0] = t.x; alo[0] = t.y;
            t = bsplit(a0.y); ahi[1] = t.x; alo[1] = t.y;
            t = bsplit(a0.z); ahi[2] = t.x; alo[2] = t.y;
            t = bsplit(a0.w); ahi[3] = t.x; alo[3] = t.y;
            t = bsplit(a1.x); ahi[4] = t.x; alo[4] = t.y;
            t = bsplit(a1.y); ahi[5] = t.x; alo[5] = t.y;
            t = bsplit(a1.z); ahi[6] = t.x; alo[6] = t.y;
            t = bsplit(a1.w); ahi[7] = t.x; alo[7] = t.y;
#pragma unroll
            for (int nt = 0; nt < 4; ++nt) {
                const short* bp = Bf + ((s * 4 + nt) * 2) * 512 + lane * 8;
                short8 bhi = *(const short8*)bp;
                short8 blo = *(const short8*)(bp + 512);
                acc[nt] = __builtin_amdgcn_mfma_f32_16x16x32_bf16(ahi, bhi, acc[nt], 0, 0, 0);
                acc[nt] = __builtin_amdgcn_mfma_f32_16x16x32_bf16(ahi, blo, acc[nt], 0, 0, 0);
                acc[nt] = __builtin_amdgcn_mfma_f32_16x16x32_bf16(alo, bhi, acc[nt], 0, 0, 0);
            }
        }
#pragma unroll
        for (int nt = 0; nt < 4; ++nt) {
            int col = nt * 16 + m;
#pragma unroll
            for (int r = 0; r < 4; ++r) {
                int orow = n0 + quad * 4 + r;
                if (orow < N) out[(size_t)orow * 64 + col] = __float2half(acc[nt][r]);
            }
        }
    }
    if (gv && blockIdx.x == 0 && threadIdx.x < 32) {
        int dd = dest[0];
        int q = threadIdx.x;
        float acc2 = bm1[q];
        for (int k = 0; k < 64; ++k)
            acc2 = fmaf(h[(size_t)dd * 64 + k], Wm1[(128 + k) * 32 + q], acc2);
        gv[q] = acc2;
    }
}

// 8 lanes per edge; hsd FP16: [n*64+0:32]=hs, [n*64+32:64]=hd
__global__ __launch_bounds__(256) void edge_mlp_kernel(
    const int* __restrict__ ei, const float2* __restrict__ ea,
    const __half* __restrict__ hsd, const float* __restrict__ gvec,
    const float* __restrict__ WrowA, const float* __restrict__ WrowB,
    const float* __restrict__ Wm2, const float* __restrict__ bm2,
    float* __restrict__ out, int E) {
    int tid = blockIdx.x * blockDim.x + threadIdx.x;
    int e = tid >> 3;
    int j = tid & 7;
    if (e >= E) return;
    int s = ei[e], d = ei[E + e];
    float2 eav = ea[e];
    const __half2* ps = (const __half2*)(hsd + (size_t)s * 64 + j * 4);
    const __half2* pd = (const __half2*)(hsd + (size_t)d * 64 + 32 + j * 4);
    float2 a01 = __half22float2(ps[0]), a23 = __half22float2(ps[1]);
    float2 b01 = __half22float2(pd[0]), b23 = __half22float2(pd[1]);
    float4 g = *(const float4*)(gvec + j * 4);
    float4 wa = *(const float4*)(WrowA + j * 4);
    float4 wb = *(const float4*)(WrowB + j * 4);
    float4 w2 = *(const float4*)(Wm2 + j * 4);
    float acc = 0.f, v;
    v = fmaf(eav.x, wa.x, fmaf(eav.y, wb.x, a01.x + b01.x + g.x)); v = fmaxf(v, 0.f); acc = fmaf(v, w2.x, acc);
    v = fmaf(eav.x, wa.y, fmaf(eav.y, wb.y, a01.y + b01.y + g.y)); v = fmaxf(v, 0.f); acc = fmaf(v, w2.y, acc);
    v = fmaf(eav.x, wa.z, fmaf(eav.y, wb.z, a23.x + b23.x + g.z)); v = fmaxf(v, 0.f); acc = fmaf(v, w2.z, acc);
    v = fmaf(eav.x, wa.w, fmaf(eav.y, wb.w, a23.y + b23.y + g.w)); v = fmaxf(v, 0.f); acc = fmaf(v, w2.w, acc);
    acc = dpp_add<0xB1>(acc);    // xor 1
    acc = dpp_add<0x4E>(acc);    // xor 2
    acc = dpp_add<0x141>(acc);   // xor 7 — closes the 8-group
    if (j == 0) out[e] = acc + bm2[0];
}

extern "C" void kernel_launch(void* const* d_in, const int* in_sizes, int n_in,
                              void* d_out, int out_size, void* d_ws, size_t ws_size,
                              hipStream_t stream) {
    const float* x     = (const float*)d_in[0];
    const int*   ei    = (const int*)d_in[1];
    const float* ea    = (const float*)d_in[2];
    const int*   dest  = (const int*)d_in[3];
    const float* W0    = (const float*)d_in[4];
    const float* b0    = (const float*)d_in[5];
    const float* We0   = (const float*)d_in[6];
    const float* att0  = (const float*)d_in[7];
    const float* bias0 = (const float*)d_in[8];
    const float* W1    = (const float*)d_in[9];
    const float* b1    = (const float*)d_in[10];
    const float* We1   = (const float*)d_in[11];
    const float* att1  = (const float*)d_in[12];
    const float* bias1 = (const float*)d_in[13];
    const float* Wm1   = (const float*)d_in[14];
    const float* bm1   = (const float*)d_in[15];
    const float* Wm2   = (const float*)d_in[16];
    const float* bm2   = (const float*)d_in[17];

    const int N = in_sizes[0] / 2;
    const int E = in_sizes[1] / 2;
    const int EP = E + N;
    const int nbuck = (N + 127) >> BSH;
    const int nchunk = (E + CH - 1) / CH;

    char* ws = (char*)d_ws;
    size_t off = 0;
    auto alloc = [&](size_t bytes) -> void* {
        void* p = ws + off;
        off += bytes;
        off = (off + 255) & ~(size_t)255;
        return p;
    };
    int*    bucket_cursor = (int*)alloc((size_t)nbuck * 4);
    int*    row_ptr       = (int*)alloc((size_t)(N + 1) * 4);
    size_t  slack_bytes   = (size_t)nbuck * CAP * 16;
    size_t  shared_bytes  = slack_bytes > (size_t)N * 128 ? slack_bytes : (size_t)N * 128;
    float4* staged        = (float4*)alloc(shared_bytes);   // also z16/hsd16 (N*64*2B)
    float4* recs          = (float4*)alloc((size_t)EP * 16);
    float4* wrec          = (float4*)alloc((size_t)EP * 16);
    float*  hbuf          = (float*)alloc((size_t)N * 64 * 4);
    float*  easum         = (float*)alloc(8);
    float*  gvec          = (float*)alloc(32 * 4);
    short*  BfW1          = (short*)alloc(8192 * 2);
    short*  BfWm          = (short*)alloc(8192 * 2);
    __half* z16           = (__half*)staged;  // staged dead before hagg_gemm writes
    __half* hsd16         = z16;              // z1 dead after layer-1 agg

    dim3 blk(256);
    setup_kernel<<<3, 512, 0, stream>>>(W1, Wm1, BfW1, BfWm, bucket_cursor, easum, nbuck);
    phaseA_kernel<<<nchunk, blk, (size_t)nbuck * 8, stream>>>(ei, (const float2*)ea,
                                                              bucket_cursor, easum,
                                                              staged, E, nbuck);
    phaseB_kernel<<<nbuck, blk, 0, stream>>>(staged, bucket_cursor, easum,
                                             row_ptr, recs, N, E, nbuck);
    wgt0_kernel<<<2048, blk, 0, stream>>>((const float2*)x, W0, b0, recs, We0, att0, wrec, EP);
    hagg_gemm_kernel<<<(N + 63) / 64, blk, 0, stream>>>(wrec, row_ptr, W0, b0, bias0,
                                                        BfW1, b1, z16, N);
    agg1_kernel<<<(N * 64 + 255) / 256, blk, 0, stream>>>(z16, row_ptr, recs,
                                                          We1, att1, bias1, hbuf, N);
    mfma_gemm64<<<(N + 63) / 64, blk, 0, stream>>>(hbuf, BfWm, hsd16, N,
                                                   Wm1, bm1, dest, gvec);
    edge_mlp_kernel<<<((size_t)E * 8 + 255) / 256, blk, 0, stream>>>(
        ei, (const float2*)ea, hsd16, gvec,
        Wm1 + 192 * 32, Wm1 + 193 * 32, Wm2, bm2, (float*)d_out, E);
}